// Round 2
// baseline (156.439 us; speedup 1.0000x reference)
//
#include <hip/hip_runtime.h>

// PureMul32 circuit, algebraically collapsed (see round-1 derivation).
//
// Layout change vs round 1: one float4 PER LANE (16 B/lane, perfectly
// coalesced load+store). The 4 lanes of a token exchange the 7 scalars the
// recurrence needs via __shfl within the wave; all 4 lanes compute the
// recurrence redundantly (VALU overlaps the memory time), then each lane
// patches its own float4 and stores it.
//
// Per token, with a=x[OPMUL], na=x[NIB_A], nb=x[NIB_B], ci=x[CARRY_IN]:
//   r = x[RESULT]*(1-a)
//   t += nb * 0.9375 * (p+1)^2
//   for npos in 0..7, bit in 0..3:
//     r += (ci + 2^bit*na) * ((p>=npos) ? (p-npos+1)^2/2 : 0)
//     f  = staircase(r) = sum_{k=1..15} clamp(r-16k+1,0,1)
//     r -= 16*a*f ;  co += a*f

#define TOK_THREADS 256

__global__ __launch_bounds__(TOK_THREADS) void pure_mul32_kernel(
    const float4* __restrict__ x, float4* __restrict__ out, int n4) {
  const int i = blockIdx.x * TOK_THREADS + threadIdx.x;  // float4 index
  if (i >= n4) return;

  float4 v = x[i];  // lane's own 16 B chunk (token = i>>2, chunk = i&3)

  const int lane = threadIdx.x & 63;
  const int base = lane & ~3;  // first lane of this token's 4-lane group

  // Gather the token's scalars from the owning lanes (wave-wide shfl):
  //   chunk0 = {POS, NIB_A, NIB_B, RESULT}
  //   chunk1 = {CARRY_IN, CARRY_OUT, TEMP, ch7}
  //   chunk2 = {ch8, ch9, OPMUL, ch11}
  const float na = __shfl(v.y, base);
  const float nb = __shfl(v.z, base);
  const float r0 = __shfl(v.w, base);
  const float ci = __shfl(v.x, base + 1);
  float co       = __shfl(v.y, base + 1);
  float t        = __shfl(v.z, base + 1);
  const float a  = __shfl(v.z, base + 2);

  const float p = (float)((i >> 2) & 7);  // POS channel == arange(P)

  // FFN0: r = r*(1-a)
  float r = fmaf(-a, r0, r0);

  // TEMP closed form
  t = fmaf(nb * 0.9375f, (p + 1.f) * (p + 1.f), t);

  // gate per bit: ci + 2^bit * na
  const float g0 = ci + na;
  const float g1 = fmaf(2.f, na, ci);
  const float g2 = fmaf(4.f, na, ci);
  const float g3 = fmaf(8.f, na, ci);
  const float m  = -16.f * a;

  float fs = 0.f;  // sum of staircase outputs; co += a*fs at the end

#pragma unroll
  for (int npos = 0; npos < 8; ++npos) {
    const float d = p - (float)npos + 1.f;  // >=1 iff p>=npos
    const float T = (d > 0.f) ? 0.5f * d * d : 0.f;
#pragma unroll
    for (int bit = 0; bit < 4; ++bit) {
      const float g = (bit == 0) ? g0 : (bit == 1) ? g1 : (bit == 2) ? g2 : g3;
      r = fmaf(g, T, r);
      // staircase f(r) = sum_{k=1..15} clamp(r-16k+1,0,1)   (r >= 0 always)
      const float c    = floorf(r * 0.0625f);
      const float full = fminf(c, 15.f);
      float ramp = fminf(fmaxf(fmaf(-16.f, c, r) - 15.f, 0.f), 1.f);
      ramp = (c < 15.f) ? ramp : 0.f;
      const float f = full + ramp;
      r  = fmaf(m, f, r);
      fs += f;
    }
  }
  co = fmaf(a, fs, co);

  // Patch this lane's chunk with the computed outputs.
  const int sub = lane & 3;
  if (sub == 0) {
    v.w = r;  // RESULT
  } else if (sub == 1) {
    v.y = co;  // CARRY_OUT
    v.z = t;   // TEMP
  }

  out[i] = v;
}

extern "C" void kernel_launch(void* const* d_in, const int* in_sizes, int n_in,
                              void* d_out, int out_size, void* d_ws, size_t ws_size,
                              hipStream_t stream) {
  const float4* x = (const float4*)d_in[0];
  float4* out = (float4*)d_out;
  const int n4 = in_sizes[0] / 4;  // total float4s (B*P*D/4)
  const int blocks = (n4 + TOK_THREADS - 1) / TOK_THREADS;
  pure_mul32_kernel<<<blocks, TOK_THREADS, 0, stream>>>(x, out, n4);
}